// Round 2
// 717.772 us; speedup vs baseline: 1.1177x; 1.1177x over previous
//
#include <hip/hip_runtime.h>
#include <stdint.h>

#define TT     914
#define BB     2048
#define DICTN  4880
#define MAXLEN 6
#define HENC_OFF ((size_t)BB * MAXLEN * DICTN)

// ---------- bf16 helpers (raw uint16 storage) ----------
__device__ __forceinline__ float bf2f(uint16_t u) {
    union { uint32_t i; float f; } v; v.i = ((uint32_t)u) << 16; return v.f;
}
__device__ __forceinline__ float bf2f_lo(uint32_t d) {
    union { uint32_t i; float f; } v; v.i = d << 16; return v.f;
}
__device__ __forceinline__ float bf2f_hi(uint32_t d) {
    union { uint32_t i; float f; } v; v.i = d & 0xFFFF0000u; return v.f;
}
__device__ __forceinline__ uint16_t f2bf(float f) {
    union { uint32_t i; float f; } v; v.f = f;
    uint32_t i = v.i;
    uint32_t r = i + 0x7FFFu + ((i >> 16) & 1u);   // RNE
    return (uint16_t)(r >> 16);
}

// Fast nonlinearities: v_exp_f32 + v_rcp_f32 (1 ulp) instead of IEEE divide
// (div_scale/div_fmas/div_fixup sequence). ~10 instrs + ~30cy latency saved
// per divide, 3 divides per GRU step.
__device__ __forceinline__ float fsigmoid(float x) {
    return __builtin_amdgcn_rcpf(1.0f + __expf(-x));
}
__device__ __forceinline__ float ftanh(float x) {
    return fmaf(-2.0f, __builtin_amdgcn_rcpf(1.0f + __expf(2.0f * x)), 1.0f);
}

#define DOT4(W, a0, a1, a2, a3, b) \
    fmaf((W)[0], (a0), fmaf((W)[1], (a1), fmaf((W)[2], (a2), fmaf((W)[3], (a3), (b)))))

// ---------- VALU-pipe cross-lane primitives (no LDS pipe!) ----------
// DPP quad_perm: xor within the 4-lane quad. 1 VALU instr, ~4cy latency.
#define DPP_XOR1 0xB1   // quad_perm:[1,0,3,2]
#define DPP_XOR2 0x4E   // quad_perm:[2,3,0,1]
#define DPP_XOR3 0x1B   // quad_perm:[3,2,1,0]

template<int CTRL>
__device__ __forceinline__ int dpp_i(int v) {
    return __builtin_amdgcn_mov_dpp(v, CTRL, 0xF, 0xF, true);
}
template<int CTRL>
__device__ __forceinline__ float dpp_f(float v) {
    return __int_as_float(dpp_i<CTRL>(__float_as_int(v)));
}

// gfx950 v_permlane32_swap_b32: VALU cross-half exchange.
// r[0] = v[lane & 31] (lo half replicated), r[1] = v[lane | 32] (hi half).
typedef unsigned int uvec2 __attribute__((ext_vector_type(2)));

__device__ __forceinline__ float from_lo(float v) {   // value of lane&31
    uvec2 r = __builtin_amdgcn_permlane32_swap(__float_as_uint(v),
                                               __float_as_uint(v), false, false);
    return __uint_as_float(r[0]);
}
__device__ __forceinline__ float xhalf_f(float v, bool hi) {   // value of lane^32
    uvec2 r = __builtin_amdgcn_permlane32_swap(__float_as_uint(v),
                                               __float_as_uint(v), false, false);
    return __uint_as_float(hi ? r[0] : r[1]);
}
__device__ __forceinline__ int xhalf_i(int v, bool hi) {
    uvec2 r = __builtin_amdgcn_permlane32_swap((unsigned int)v,
                                               (unsigned int)v, false, false);
    return (int)(hi ? r[0] : r[1]);
}

// x-stream vector type: covers 2 timesteps either way
template<bool F32> struct XVT { using T = uint2;  };   // 4 bf16 = 2 steps
template<>         struct XVT<true> { using T = float4; };  // 4 f32 = 2 steps

template<bool F32>
__device__ __forceinline__ float ldw(const void* p, int i) {
    if constexpr (F32) return ((const float*)p)[i];
    else               return bf2f(((const uint16_t*)p)[i]);
}

// =====================================================================
// Fused encoder (2-layer GRU) + greedy 6-step decoder.
// Lane layout: j = lane&3 (hidden idx), bgrp = (lane>>2)&7 (batch in
// block), layer = lane>>5.  All cross-lane traffic is VALU-pipe:
//   - intra-quad allgather: DPP quad_perm  (was ds-pipe __shfl_xor 1/2)
//   - layer0->layer1 forward: v_permlane32_swap_b32 (was __shfl_xor 4)
// Hidden state kept xor-allgathered: hv[m] = h[j^m]; weights pre-permuted.
// =====================================================================
template<bool F32>
__device__ __forceinline__ void t2s_body(
    const void* __restrict__ x,
    const void* __restrict__ eWih0, const void* __restrict__ eWhh0,
    const void* __restrict__ ebih0, const void* __restrict__ ebhh0,
    const void* __restrict__ eWih1, const void* __restrict__ eWhh1,
    const void* __restrict__ ebih1, const void* __restrict__ ebhh1,
    const void* __restrict__ dWih0, const void* __restrict__ dWhh0,
    const void* __restrict__ dbih0, const void* __restrict__ dbhh0,
    const void* __restrict__ dWih1, const void* __restrict__ dWhh1,
    const void* __restrict__ dbih1, const void* __restrict__ dbhh1,
    const void* __restrict__ emb,
    const void* __restrict__ fc1W, const void* __restrict__ fc1b,
    void* __restrict__ out)
{
    const int  lane  = threadIdx.x;
    const int  j     = lane & 3;
    const int  bgrp  = (lane >> 2) & 7;
    const bool is_l1 = (lane >= 32);          // layer lives in wave halves now
    const int  b     = blockIdx.x * 8 + bgrp;

    float p0, p1, p2, p3, q0, q1, q2, q3;     // decoder h0/h1 state, hv form

    // ================= encoder =================
    {
        const void* Wih = is_l1 ? eWih1 : eWih0;
        const void* Whh = is_l1 ? eWhh1 : eWhh0;
        const void* bip = is_l1 ? ebih1 : ebih0;
        const void* bhp = is_l1 ? ebhh1 : ebhh0;

        float Wi[3][4], Wh[3][4], bi[3], bh[3];
        #pragma unroll
        for (int g = 0; g < 3; ++g) {
            const int row = g * 4 + j;        // gate order (r,z,n)
            bi[g] = ldw<F32>(bip, row);
            bh[g] = ldw<F32>(bhp, row);
            #pragma unroll
            for (int m = 0; m < 4; ++m)
                Wh[g][m] = ldw<F32>(Whh, row * 4 + (j ^ m));
            if (is_l1) {
                #pragma unroll
                for (int m = 0; m < 4; ++m)
                    Wi[g][m] = ldw<F32>(Wih, row * 4 + (j ^ m));  // input = allgathered h0
            } else {
                Wi[g][0] = ldw<F32>(Wih, row * 2 + 0);            // input = (x0,x1,0,0)
                Wi[g][1] = ldw<F32>(Wih, row * 2 + 1);
                Wi[g][2] = 0.0f; Wi[g][3] = 0.0f;
            }
        }

        using XV = typename XVT<F32>::T;
        const XV* __restrict__ xp =
            (const XV*)((const char*)x + (size_t)b * (TT * 2) * (F32 ? 4 : 2));

        float hv0 = 0.f, hv1 = 0.f, hv2 = 0.f, hv3 = 0.f;   // hv[m] = h[j^m]
        float xf0 = 0.f, xf1 = 0.f, xf2 = 0.f, xf3 = 0.f;   // layer0-half hv (for layer1)

        XV bufA_lo = xp[0], bufA_hi = xp[1];   // chunk = 4 steps = two XVs
        XV bufB_lo = xp[2], bufB_hi = xp[3];
        const XV xt = xp[456];                 // t=912,913

        for (int c = 0; c < 229; ++c) {        // 229 chunks x 4 = 916 iterations
            XV lo = bufA_lo, hi = bufA_hi;
            bufA_lo = bufB_lo; bufA_hi = bufB_hi;
            const int ci = min(c + 2, 227);    // clamped prefetch, in-bounds
            bufB_lo = xp[2 * ci];
            bufB_hi = xp[2 * ci + 1];

            if (c == 228) lo = xt;             // steps 0,1 = t912,913; 2,3 inactive

            #pragma unroll
            for (int s = 0; s < 4; ++s) {
                const int it = c * 4 + s;
                float x0, x1;
                if constexpr (F32) {
                    const float4 v = (s < 2) ? lo : hi;
                    x0 = (s & 1) ? v.z : v.x;
                    x1 = (s & 1) ? v.w : v.y;
                } else {
                    const uint32_t w = (s < 2) ? ((s & 1) ? lo.y : lo.x)
                                               : ((s & 1) ? hi.y : hi.x);
                    x0 = bf2f_lo(w); x1 = bf2f_hi(w);
                }

                const float in0 = is_l1 ? xf0 : x0;
                const float in1 = is_l1 ? xf1 : x1;
                const float in2 = is_l1 ? xf2 : 0.0f;
                const float in3 = is_l1 ? xf3 : 0.0f;

                const float gr = DOT4(Wi[0], in0, in1, in2, in3, bi[0]);
                const float gz = DOT4(Wi[1], in0, in1, in2, in3, bi[1]);
                const float gn = DOT4(Wi[2], in0, in1, in2, in3, bi[2]);
                const float hr = DOT4(Wh[0], hv0, hv1, hv2, hv3, bh[0]);
                const float hz = DOT4(Wh[1], hv0, hv1, hv2, hv3, bh[1]);
                const float hn = DOT4(Wh[2], hv0, hv1, hv2, hv3, bh[2]);

                const float r = fsigmoid(gr + hr);
                const float z = fsigmoid(gz + hz);
                const float n = ftanh(fmaf(r, hn, gn));
                const float hnew = fmaf(z, hv0 - n, n);

                // layer0 active it<914 (consumes x_it); layer1 active 1<=it<=914
                const bool act = is_l1 ? (it >= 1 && it < 915) : (it < 914);
                const float hj = act ? hnew : hv0;

                // allgather within quad: 3 independent DPP movs (VALU pipe)
                hv0 = hj;
                hv1 = dpp_f<DPP_XOR1>(hj);
                hv2 = dpp_f<DPP_XOR2>(hj);
                hv3 = dpp_f<DPP_XOR3>(hj);
                // layer0 -> layer1 forward: one permlane32_swap + 3 DPP.
                // xf0 = layer0-half's hj (own value in lo lanes, never
                // consumed there); xf[m] = quad-perm family of xf0.
                xf0 = from_lo(hj);
                xf1 = dpp_f<DPP_XOR1>(xf0);
                xf2 = dpp_f<DPP_XOR2>(xf0);
                xf3 = dpp_f<DPP_XOR3>(xf0);
            }
        }

        // h_enc output (2, B, 4)
        const size_t hidx = HENC_OFF + ((size_t)(is_l1 ? 1 : 0) * BB + b) * 4 + j;
        if constexpr (F32) ((float*)out)[hidx] = hv0;
        else               ((uint16_t*)out)[hidx] = f2bf(hv0);

        // decoder init: full cross-half exchange (once, outside the hot loop)
        const float o0 = xhalf_f(hv0, is_l1);
        const float o1 = xhalf_f(hv1, is_l1);
        const float o2 = xhalf_f(hv2, is_l1);
        const float o3 = xhalf_f(hv3, is_l1);
        p0 = is_l1 ? o0 : hv0;  p1 = is_l1 ? o1 : hv1;
        p2 = is_l1 ? o2 : hv2;  p3 = is_l1 ? o3 : hv3;
        q0 = is_l1 ? hv0 : o0;  q1 = is_l1 ? hv1 : o1;
        q2 = is_l1 ? hv2 : o2;  q3 = is_l1 ? hv3 : o3;
    }

    // ================= decoder =================
    float Wi0[3][4], Wh0[3][4], bi0[3], bh0[3];
    float Wi1[3][4], Wh1[3][4], bi1[3], bh1[3];
    #pragma unroll
    for (int g = 0; g < 3; ++g) {
        const int row = g * 4 + j;
        bi0[g] = ldw<F32>(dbih0, row);  bh0[g] = ldw<F32>(dbhh0, row);
        bi1[g] = ldw<F32>(dbih1, row);  bh1[g] = ldw<F32>(dbhh1, row);
        #pragma unroll
        for (int m = 0; m < 4; ++m) {
            Wi0[g][m] = ldw<F32>(dWih0, row * 4 + m);          // input = emb, natural
            Wh0[g][m] = ldw<F32>(dWhh0, row * 4 + (j ^ m));    // h0 in hv form
            Wi1[g][m] = ldw<F32>(dWih1, row * 4 + (j ^ m));    // h0' in hv form
            Wh1[g][m] = ldw<F32>(dWhh1, row * 4 + (j ^ m));    // h1 in hv form
        }
    }

    const int sub2 = j | (is_l1 ? 4 : 0);      // 8-way dict partition per batch elem

    int tok = 0;
    for (int st = 0; st < MAXLEN; ++st) {
        float e0, e1, e2, e3;
        if constexpr (F32) {
            const float4 ev = *(const float4*)((const float*)emb + (size_t)tok * 4);
            e0 = ev.x; e1 = ev.y; e2 = ev.z; e3 = ev.w;
        } else {
            const uint2 ev = *(const uint2*)((const uint16_t*)emb + (size_t)tok * 4);
            e0 = bf2f_lo(ev.x); e1 = bf2f_hi(ev.x);
            e2 = bf2f_lo(ev.y); e3 = bf2f_hi(ev.y);
        }

        {   // cell0: h0' = GRU(e, p)
            const float gr = DOT4(Wi0[0], e0, e1, e2, e3, bi0[0]);
            const float gz = DOT4(Wi0[1], e0, e1, e2, e3, bi0[1]);
            const float gn = DOT4(Wi0[2], e0, e1, e2, e3, bi0[2]);
            const float hr = DOT4(Wh0[0], p0, p1, p2, p3, bh0[0]);
            const float hz = DOT4(Wh0[1], p0, p1, p2, p3, bh0[1]);
            const float hn = DOT4(Wh0[2], p0, p1, p2, p3, bh0[2]);
            const float r = fsigmoid(gr + hr);
            const float z = fsigmoid(gz + hz);
            const float n = ftanh(fmaf(r, hn, gn));
            const float hnew = fmaf(z, p0 - n, n);
            p0 = hnew;
            p1 = dpp_f<DPP_XOR1>(hnew);
            p2 = dpp_f<DPP_XOR2>(hnew);
            p3 = dpp_f<DPP_XOR3>(hnew);
        }
        {   // cell1: h1' = GRU(h0', q)
            const float gr = DOT4(Wi1[0], p0, p1, p2, p3, bi1[0]);
            const float gz = DOT4(Wi1[1], p0, p1, p2, p3, bi1[1]);
            const float gn = DOT4(Wi1[2], p0, p1, p2, p3, bi1[2]);
            const float hr = DOT4(Wh1[0], q0, q1, q2, q3, bh1[0]);
            const float hz = DOT4(Wh1[1], q0, q1, q2, q3, bh1[1]);
            const float hn = DOT4(Wh1[2], q0, q1, q2, q3, bh1[2]);
            const float r = fsigmoid(gr + hr);
            const float z = fsigmoid(gz + hz);
            const float n = ftanh(fmaf(r, hn, gn));
            const float hnew = fmaf(z, q0 - n, n);
            q0 = hnew;
            q1 = dpp_f<DPP_XOR1>(hnew);
            q2 = dpp_f<DPP_XOR2>(hnew);
            q3 = dpp_f<DPP_XOR3>(hnew);
        }

        // natural-order h1': a[k] = q[k ^ j]
        const bool jb0 = (j & 1) != 0, jb1 = (j & 2) != 0;
        const float s0 = jb0 ? q1 : q0, s1 = jb0 ? q0 : q1;
        const float s2 = jb0 ? q3 : q2, s3 = jb0 ? q2 : q3;
        const float a0 = jb1 ? s2 : s0, a1 = jb1 ? s3 : s1;
        const float a2 = jb1 ? s0 : s2, a3 = jb1 ? s1 : s3;

        const size_t off = ((size_t)b * MAXLEN + st) * DICTN;
        float best = -3.4e38f;
        int   bidx = 0;                         // safe default

        for (int db = sub2; db < DICTN / 8; db += 8) {   // 610 blocks of 8 dicts
            const int d0 = db * 8;
            float l[8];
            if constexpr (F32) {
                const float4* wr = (const float4*)((const float*)fc1W + (size_t)d0 * 4);
                const float4 bv0 = *(const float4*)((const float*)fc1b + d0);
                const float4 bv1 = *(const float4*)((const float*)fc1b + d0 + 4);
                const float bb[8] = { bv0.x, bv0.y, bv0.z, bv0.w,
                                      bv1.x, bv1.y, bv1.z, bv1.w };
                #pragma unroll
                for (int i = 0; i < 8; ++i) {
                    const float4 w = wr[i];
                    l[i] = fmaf(a0, w.x, fmaf(a1, w.y, fmaf(a2, w.z, fmaf(a3, w.w, bb[i]))));
                }
                float* op = (float*)out + off + d0;
                *(float4*)(op)     = float4{ l[0], l[1], l[2], l[3] };
                *(float4*)(op + 4) = float4{ l[4], l[5], l[6], l[7] };
            } else {
                const uint4* wp = (const uint4*)((const uint16_t*)fc1W + (size_t)d0 * 4);
                const uint4 w0 = wp[0], w1 = wp[1], w2 = wp[2], w3 = wp[3];
                const uint4 bv = *(const uint4*)((const uint16_t*)fc1b + d0);
                const uint32_t wa[16] = { w0.x, w0.y, w0.z, w0.w,
                                          w1.x, w1.y, w1.z, w1.w,
                                          w2.x, w2.y, w2.z, w2.w,
                                          w3.x, w3.y, w3.z, w3.w };
                const uint32_t ba[4] = { bv.x, bv.y, bv.z, bv.w };
                #pragma unroll
                for (int i = 0; i < 8; ++i) {
                    const uint32_t da  = wa[2 * i];
                    const uint32_t db2 = wa[2 * i + 1];
                    float acc = (i & 1) ? bf2f_hi(ba[i >> 1]) : bf2f_lo(ba[i >> 1]);
                    acc = fmaf(a0, bf2f_lo(da), acc);
                    acc = fmaf(a1, bf2f_hi(da), acc);
                    acc = fmaf(a2, bf2f_lo(db2), acc);
                    acc = fmaf(a3, bf2f_hi(db2), acc);
                    l[i] = acc;
                }
                uint4 ov;
                ov.x = (uint32_t)f2bf(l[0]) | ((uint32_t)f2bf(l[1]) << 16);
                ov.y = (uint32_t)f2bf(l[2]) | ((uint32_t)f2bf(l[3]) << 16);
                ov.z = (uint32_t)f2bf(l[4]) | ((uint32_t)f2bf(l[5]) << 16);
                ov.w = (uint32_t)f2bf(l[6]) | ((uint32_t)f2bf(l[7]) << 16);
                *(uint4*)((uint16_t*)out + off + d0) = ov;
            }
            #pragma unroll
            for (int i = 0; i < 8; ++i) {
                if (l[i] > best) { best = l[i]; bidx = d0 + i; }   // first-max
            }
        }

        // argmax reduce across the 8 lanes of this batch elem:
        // quad-internal (xor1, xor2) via DPP, cross-half via permlane32_swap.
        {
            const float ov = dpp_f<DPP_XOR1>(best);
            const int   oi = dpp_i<DPP_XOR1>(bidx);
            if (ov > best || (ov == best && oi < bidx)) { best = ov; bidx = oi; }
        }
        {
            const float ov = dpp_f<DPP_XOR2>(best);
            const int   oi = dpp_i<DPP_XOR2>(bidx);
            if (ov > best || (ov == best && oi < bidx)) { best = ov; bidx = oi; }
        }
        {
            const float ov = xhalf_f(best, is_l1);
            const int   oi = xhalf_i(bidx, is_l1);
            if (ov > best || (ov == best && oi < bidx)) { best = ov; bidx = oi; }
        }
        // SAFETY CLAMP: never index emb out of range, even with NaN logits
        tok = ((unsigned)bidx < (unsigned)DICTN) ? bidx : 0;
    }
}

__global__ __launch_bounds__(64, 1) void t2s_fused(
    const void* __restrict__ x,
    const void* __restrict__ eWih0, const void* __restrict__ eWhh0,
    const void* __restrict__ ebih0, const void* __restrict__ ebhh0,
    const void* __restrict__ eWih1, const void* __restrict__ eWhh1,
    const void* __restrict__ ebih1, const void* __restrict__ ebhh1,
    const void* __restrict__ dWih0, const void* __restrict__ dWhh0,
    const void* __restrict__ dbih0, const void* __restrict__ dbhh0,
    const void* __restrict__ dWih1, const void* __restrict__ dWhh1,
    const void* __restrict__ dbih1, const void* __restrict__ dbhh1,
    const void* __restrict__ emb,
    const void* __restrict__ fc1W, const void* __restrict__ fc1b,
    void* __restrict__ out)
{
    // ---- dtype probe on enc_Whh0 (48 elements known ~N(0,0.2)) ----
    // Even uint16 indices: bf16 data -> plausible magnitudes; f32 data ->
    // low-mantissa garbage with random exponent. Count in-range samples.
    const uint16_t* pw = (const uint16_t*)eWhh0;
    int cnt = 0;
    #pragma unroll
    for (int k = 0; k < 12; ++k) {
        const float av = fabsf(bf2f(pw[2 * k]));
        if (av >= 0.000244140625f && av <= 8.0f) ++cnt;   // NaN fails both
    }
    const bool is_bf16 = (cnt >= 7);   // uniform across all threads

    if (is_bf16)
        t2s_body<false>(x, eWih0, eWhh0, ebih0, ebhh0, eWih1, eWhh1, ebih1, ebhh1,
                        dWih0, dWhh0, dbih0, dbhh0, dWih1, dWhh1, dbih1, dbhh1,
                        emb, fc1W, fc1b, out);
    else
        t2s_body<true>(x, eWih0, eWhh0, ebih0, ebhh0, eWih1, eWhh1, ebih1, ebhh1,
                       dWih0, dWhh0, dbih0, dbhh0, dWih1, dWhh1, dbih1, dbhh1,
                       emb, fc1W, fc1b, out);
}

extern "C" void kernel_launch(void* const* d_in, const int* in_sizes, int n_in,
                              void* d_out, int out_size, void* d_ws, size_t ws_size,
                              hipStream_t stream)
{
    (void)d_ws; (void)ws_size; (void)in_sizes; (void)n_in; (void)out_size;

    t2s_fused<<<BB / 8, 64, 0, stream>>>(
        d_in[0],                                   // x
        d_in[1], d_in[2], d_in[3], d_in[4],        // enc layer0
        d_in[5], d_in[6], d_in[7], d_in[8],        // enc layer1
        d_in[9], d_in[10], d_in[11], d_in[12],     // dec layer0
        d_in[13], d_in[14], d_in[15], d_in[16],    // dec layer1
        d_in[17],                                  // emb
        d_in[20], d_in[21],                        // fc1_W, fc1_b  (18,19 = fc_W,fc_b unused)
        d_out);
}